// Round 4
// baseline (11691.926 us; speedup 1.0000x reference)
//
#include <hip/hip_runtime.h>
#include <cstdint>

#define B_SZ   2048
#define T_SZ   80
#define VOCABN 80
#define EMBN   8
#define HID    256
#define G4     1024
#define GTILE  64              // batch rows per group
#define NGRP   32              // groups
#define GBLK   8               // blocks per group
#define NBLKS  (NGRP * GBLK)   // 256 = one per CU
#define NTHR   512
#define NPHASE 176             // per-group phase slots (2*T_SZ used)
#define GSTR   132             // gates LDS row stride (f32), pad kills 4-way bank conflict

typedef __bf16 bf16;
typedef __attribute__((ext_vector_type(8))) __bf16 bf16x8;
typedef __attribute__((ext_vector_type(4))) float  f32x4;

__device__ __forceinline__ float sigf(float x)   { return 1.0f / (1.0f + __expf(-x)); }
__device__ __forceinline__ float tanhf2(float x) { return 1.0f - 2.0f / (__expf(2.0f * x) + 1.0f); }

__device__ __forceinline__ unsigned short f2bf(float f) {
    union { float f; unsigned int u; } v; v.f = f;
    unsigned int u = v.u;
    return (unsigned short)((u + 0x7FFFu + ((u >> 16) & 1u)) >> 16);
}
__device__ __forceinline__ float bf2f(unsigned short h) {
    union { unsigned int u; float f; } v; v.u = ((unsigned int)h) << 16;
    return v.f;
}

// Swizzled h-tile addressing (verified R1/R2): [64][256] bf16, 16B blocks rotated by 2*row.
#define HSWZ(row, col) ((row) * 256 + (((((col) >> 3) + 2 * (row)) & 31) << 3) + ((col) & 7))

// ---------------- ws layout (bytes) ----------------
#define EG_OFF   0u
#define WP_OFF   327680u
#define SL1_OFF  1900544u
#define SL2_OFF  3997696u
#define CTR_OFF  6094848u
#define CTR_BYTES (NGRP * NPHASE * 4)

// ---------------- prep kernels ----------------
__global__ void prep_eg(const float* __restrict__ emb, const float* __restrict__ W1,
                        const float* __restrict__ b1, float* __restrict__ eg) {
    int idx = blockIdx.x * blockDim.x + threadIdx.x;
    if (idx >= VOCABN * G4) return;
    int v = idx >> 10, n = idx & 1023;
    float s = b1[n];
#pragma unroll
    for (int e = 0; e < EMBN; ++e) s += emb[v * EMBN + e] * W1[e * G4 + n];
    eg[idx] = s;
}

// wp: [nt(64)][k(24)][lane(64)][8] bf16.  Packed col G = nt*16 + (lane&15);
// gate = G&3, hcol = G>>2, source col = gate*256 + hcol (gate-interleaved packing).
// k 0..7: W1 h-rows (offset EMBN); k 8..15: W2 x-rows 0..255; k 16..23: W2 h-rows 256..511.
__global__ void prep_w(const float* __restrict__ W1, const float* __restrict__ W2,
                       unsigned short* __restrict__ wp) {
    int idx = blockIdx.x * blockDim.x + threadIdx.x;
    if (idx >= 64 * 24 * 64) return;
    int lane = idx & 63, k = (idx >> 6) % 24, nt = idx / (24 * 64);
    int G = nt * 16 + (lane & 15);
    int scol = (G & 3) * 256 + (G >> 2);
    int lg = lane >> 4;
#pragma unroll
    for (int e = 0; e < 8; ++e) {
        float val;
        if (k < 8) val = W1[(EMBN + k * 32 + lg * 8 + e) * G4 + scol];
        else       val = W2[((k - 8) * 32 + lg * 8 + e) * G4 + scol];
        wp[idx * 8 + e] = f2bf(val);
    }
}

// ---------------- group sync (XCD-safe scoped atomics) ----------------
__device__ __forceinline__ void grp_arrive(int* c) {
    __threadfence();
    __syncthreads();
    if (threadIdx.x == 0)
        __hip_atomic_fetch_add(c, 1, __ATOMIC_RELEASE, __HIP_MEMORY_SCOPE_AGENT);
}
__device__ __forceinline__ void grp_wait(int* c) {
    if (threadIdx.x == 0)
        while (__hip_atomic_load(c, __ATOMIC_ACQUIRE, __HIP_MEMORY_SCOPE_AGENT) < GBLK)
            __builtin_amdgcn_s_sleep(2);
    __syncthreads();
    __threadfence();   // acquire side: invalidate before reading partner slices
}

// ---------------- macros for the hot loop ----------------
#define ACCZ() do { _Pragma("unroll") for (int m_ = 0; m_ < 4; ++m_) acc[m_] = zf; } while (0)

#define MM(hf_, kbase) do {                                                       \
    _Pragma("unroll")                                                             \
    for (int k_ = 0; k_ < 8; ++k_) {                                              \
        _Pragma("unroll")                                                         \
        for (int m_ = 0; m_ < 4; ++m_) {                                          \
            const int row_ = m_ * 16 + lc;                                        \
            bf16x8 a_ = *(const bf16x8*)&(hf_)[row_ * 256 +                       \
                          (((4 * k_ + lg + 2 * row_) & 31) << 3)];                \
            acc[m_] = __builtin_amdgcn_mfma_f32_16x16x32_bf16(a_, wreg[(kbase) + k_], acc[m_], 0, 0, 0); \
        }                                                                         \
    }                                                                             \
} while (0)

#define GATESW() do {                                                             \
    _Pragma("unroll") for (int m_ = 0; m_ < 4; ++m_)                              \
        _Pragma("unroll") for (int r_ = 0; r_ < 4; ++r_)                          \
            gates[(m_ * 16 + lg * 4 + r_) * GSTR + wid * 16 + lc] = acc[m_][r_];  \
} while (0)

#define PW1(tt, slw) do {                                                         \
    _Pragma("unroll")                                                             \
    for (int rr = 0; rr < 4; ++rr) {                                              \
        const int row = rg4 + rr;                                                 \
        f32x4 g = *(const f32x4*)&gates[row * GSTR + hl * 4];                     \
        const int tok = toks[row * T_SZ + (tt)];                                  \
        const float* e = eg + tok * G4 + C0 + hl;                                 \
        float gi = g[0] + e[0];                                                   \
        float gj = g[1] + e[256];                                                 \
        float gf = g[2] + e[512];                                                 \
        float go = g[3] + e[768];                                                 \
        float cn = c1s[rr] * sigf(gf + 1.0f) + sigf(gi) * tanhf2(gj);             \
        float h  = tanhf2(cn) * sigf(go);                                         \
        c1s[rr] = cn;                                                             \
        unsigned short hb = f2bf(h);                                              \
        (slw)[row * 32 + hl] = hb;                                                \
        h1f[HSWZ(row, C0 + hl)] = *(bf16*)&hb;                                    \
    }                                                                             \
} while (0)

#define PW2(slw) do {                                                             \
    _Pragma("unroll")                                                             \
    for (int rr = 0; rr < 4; ++rr) {                                              \
        const int row = rg4 + rr;                                                 \
        f32x4 g = *(const f32x4*)&gates[row * GSTR + hl * 4];                     \
        float gi = g[0] + b2v[0];                                                 \
        float gj = g[1] + b2v[1];                                                 \
        float gf = g[2] + b2v[2];                                                 \
        float go = g[3] + b2v[3];                                                 \
        float cn = c2s[rr] * sigf(gf + 1.0f) + sigf(gi) * tanhf2(gj);             \
        float h  = tanhf2(cn) * sigf(go);                                         \
        c2s[rr] = cn;                                                             \
        unsigned short hb = f2bf(h);                                              \
        (slw)[row * 32 + hl] = hb;                                                \
        h2f[HSWZ(row, C0 + hl)] = *(bf16*)&hb;                                    \
    }                                                                             \
} while (0)

// copy 7 partner slices [64][32] bf16 from ws into the full h LDS tile
__device__ __forceinline__ void copy_slices(const unsigned short* __restrict__ slr,
                                            bf16* hf, int cblk, int tid) {
    for (int i = tid; i < 7 * 64 * 4; i += NTHR) {
        int ci = i >> 8;                       // 0..6
        int rem = i & 255;
        int row = rem >> 2, cb = rem & 3;
        int cp = ci + (ci >= cblk);
        bf16x8 v = *(const bf16x8*)&slr[cp * 2048 + row * 32 + cb * 8];
        int col = cp * 32 + cb * 8;
        *(bf16x8*)&hf[row * 256 + ((((col >> 3) + 2 * row) & 31) << 3)] = v;
    }
}

__global__ __launch_bounds__(NTHR, 2)
void lstm_fused(const int* __restrict__ feat, const int* __restrict__ labels,
                const float* __restrict__ eg,
                const bf16x8* __restrict__ wpv,
                const float* __restrict__ b2,
                const float* __restrict__ Wd, const float* __restrict__ bd,
                unsigned short* __restrict__ sl1, unsigned short* __restrict__ sl2,
                int* __restrict__ ctr,
                float* __restrict__ out)
{
    __shared__ __align__(16) bf16  h1f[GTILE * 256];      // 32 KB full h1 (swizzled)
    __shared__ __align__(16) bf16  h2f[GTILE * 256];      // 32 KB full h2
    __shared__ __align__(16) float gates[GTILE * GSTR];   // 33 KB pre-activation gates
    __shared__ int   toks[GTILE * T_SZ];                  // 20 KB
    __shared__ float logitb[8][VOCABN + 4];

    const int tid  = threadIdx.x;
    const int lane = tid & 63;
    const int wid  = tid >> 6;          // wave 0..7: owns packed gate-cols [wid*16, wid*16+16)
    const int lc   = lane & 15;
    const int lg   = lane >> 4;
    const int grp  = blockIdx.x & 31;   // group id (members b = grp + 32*c: same XCD if round-robin)
    const int cblk = blockIdx.x >> 5;   // block-in-group 0..7: owns h-cols [cblk*32, cblk*32+32)
    const int C0   = cblk * 32;
    const int hl   = tid & 31;          // pointwise hcol_local
    const int rg4  = (tid >> 5) * 4;    // pointwise row base

    // init LDS
    for (int i = tid; i < GTILE * 256; i += NTHR) { h1f[i] = (bf16)0.0f; h2f[i] = (bf16)0.0f; }
    for (int i = tid; i < GTILE * T_SZ; i += NTHR)
        toks[i] = feat[grp * GTILE * T_SZ + i];

    // weights: 24 bf16x8 fragments per lane = 96 VGPRs, resident for the whole kernel
    bf16x8 wreg[24];
    {
        const bf16x8* wp = wpv + ((size_t)(cblk * 8 + wid) * 24) * 64 + lane;
#pragma unroll
        for (int k = 0; k < 24; ++k) wreg[k] = wp[k * 64];
    }

    float b2v[4];
#pragma unroll
    for (int g = 0; g < 4; ++g) b2v[g] = b2[g * 256 + C0 + hl];

    const f32x4 zf = {0.f, 0.f, 0.f, 0.f};
    f32x4 acc[4];
    float c1s[4] = {0.f, 0.f, 0.f, 0.f};
    float c2s[4] = {0.f, 0.f, 0.f, 0.f};

    __syncthreads();   // h/toks ready

    unsigned short* sl1g = sl1 + grp * 2 * GBLK * 2048;
    unsigned short* sl2g = sl2 + grp * 2 * GBLK * 2048;
    int* ctrg = ctr + grp * NPHASE;

    // ---- prologue: L1(t=0) on zero h1 ----
    ACCZ(); MM(h1f, 0); GATESW(); __syncthreads();
    PW1(0, sl1g + (0 * GBLK + cblk) * 2048);
    grp_arrive(&ctrg[0]);

    for (int t = 0; t < T_SZ; ++t) {
        const int buf = t & 1;
        // L2 h-part: uses h2full(t-1), covers ex1 latency
        ACCZ(); MM(h2f, 16);
        grp_wait(&ctrg[2 * t]);
        copy_slices(sl1g + buf * GBLK * 2048, h1f, cblk, tid);
        __syncthreads();
        // L2 x-part: h1full(t) now complete
        MM(h1f, 8);
        GATESW(); __syncthreads();
        PW2(sl2g + (buf * GBLK + cblk) * 2048);
        grp_arrive(&ctrg[2 * t + 1]);
        // next step's L1: covers ex2 latency
        if (t + 1 < T_SZ) {
            const int nbuf = (t + 1) & 1;
            ACCZ(); MM(h1f, 0); GATESW(); __syncthreads();
            PW1(t + 1, sl1g + (nbuf * GBLK + cblk) * 2048);
            grp_arrive(&ctrg[2 * (t + 1)]);
        }
        grp_wait(&ctrg[2 * t + 1]);
        copy_slices(sl2g + buf * GBLK * 2048, h2f, cblk, tid);
        __syncthreads();
    }

    // ---- epilogue: block computes logits+loss for its 8 rows ----
    {
        const int rid = tid >> 6;            // 0..7
        const int v0  = tid & 63;
        const int grow = cblk * 8 + rid;     // group-local row
        for (int v = v0; v < VOCABN; v += 64) {
            float s = bd[v];
            for (int k = 0; k < HID; ++k)
                s += (float)h2f[HSWZ(grow, k)] * Wd[k * VOCABN + v];
            logitb[rid][v] = s;
        }
        __syncthreads();
        if (tid < 8) {
            float m = -1e30f;
            for (int v = 0; v < VOCABN; ++v) m = fmaxf(m, logitb[tid][v]);
            float s = 0.f;
            for (int v = 0; v < VOCABN; ++v) s += __expf(logitb[tid][v] - m);
            int lab = labels[grp * GTILE + cblk * 8 + tid];
            float loss = m + __logf(s) - logitb[tid][lab];
            atomicAdd(out, loss * (1.0f / (float)B_SZ));
        }
    }
}

extern "C" void kernel_launch(void* const* d_in, const int* in_sizes, int n_in,
                              void* d_out, int out_size, void* d_ws, size_t ws_size,
                              hipStream_t stream)
{
    (void)in_sizes; (void)n_in; (void)out_size; (void)ws_size;
    const int*   feat   = (const int*)d_in[0];
    const int*   labels = (const int*)d_in[1];
    const float* emb    = (const float*)d_in[2];
    const float* W1     = (const float*)d_in[3];
    const float* b1     = (const float*)d_in[4];
    const float* W2     = (const float*)d_in[5];
    const float* b2     = (const float*)d_in[6];
    const float* Wd     = (const float*)d_in[7];
    const float* bd     = (const float*)d_in[8];
    float* out = (float*)d_out;

    char* ws = (char*)d_ws;
    float*          eg  = (float*)(ws + EG_OFF);
    unsigned short* wp  = (unsigned short*)(ws + WP_OFF);
    unsigned short* sl1 = (unsigned short*)(ws + SL1_OFF);
    unsigned short* sl2 = (unsigned short*)(ws + SL2_OFF);
    int*            ctr = (int*)(ws + CTR_OFF);

    hipMemsetAsync(d_out, 0, sizeof(float), stream);
    hipMemsetAsync(ctr, 0, CTR_BYTES, stream);
    prep_eg<<<(VOCABN * G4 + 255) / 256, 256, 0, stream>>>(emb, W1, b1, eg);
    prep_w<<<(64 * 24 * 64) / 256, 256, 0, stream>>>(W1, W2, wp);
    lstm_fused<<<NBLKS, NTHR, 0, stream>>>(feat, labels, eg, (const bf16x8*)wp,
                                           b2, Wd, bd, sl1, sl2, ctr, out);
}

// Round 5
// 4791.357 us; speedup vs baseline: 2.4402x; 2.4402x over previous
//
#include <hip/hip_runtime.h>
#include <cstdint>

#define B_SZ   2048
#define T_SZ   80
#define VOCABN 80
#define EMBN   8
#define HID    256
#define G4     1024
#define TILE   16
#define NBLK   (B_SZ / TILE)   // 128
#define NTHR   512

typedef __bf16 bf16;
typedef __attribute__((ext_vector_type(8))) __bf16 bf16x8;
typedef __attribute__((ext_vector_type(4))) float  f32x4;

__device__ __forceinline__ float sigf(float x)   { return 1.0f / (1.0f + __expf(-x)); }
__device__ __forceinline__ float tanhf2(float x) { return 1.0f - 2.0f / (__expf(2.0f * x) + 1.0f); }

__device__ __forceinline__ unsigned short f2bf(float f) {
    union { float f; unsigned int u; } v; v.f = f;
    unsigned int u = v.u;
    return (unsigned short)((u + 0x7FFFu + ((u >> 16) & 1u)) >> 16);
}

// Swizzled h-tile (verified R1-R3): [16][256] bf16, 16B blocks rotated by 2*row.
#define HSWZ(row, col) ((row) * 256 + (((((col) >> 3) + 2 * (row)) & 31) << 3) + ((col) & 7))
// A-fragment read (verified): row=lc, k-elems (k*32 + lg*8 .. +8)
#define AFRAG(hptr, k_) (*(const bf16x8*)&(hptr)[lc * 256 + (((4 * (k_) + lg + 2 * lc) & 31) << 3)])

// ---------------- prep kernels ----------------
__global__ void prep_eg(const float* __restrict__ emb, const float* __restrict__ W1,
                        const float* __restrict__ b1, float* __restrict__ eg) {
    int idx = blockIdx.x * blockDim.x + threadIdx.x;
    if (idx >= VOCABN * G4) return;
    int v = idx >> 10, n = idx & 1023;
    float s = b1[n];
#pragma unroll
    for (int e = 0; e < EMBN; ++e) s += emb[v * EMBN + e] * W1[e * G4 + n];
    eg[idx] = s;
}

// wp: [k(24)][nt(64)][lane(64)][8] bf16, k-major (one fragment = 1KB lane-contiguous).
// k 0..7: W1 h-rows (base EMBN); k 8..23: W2 rows 0..511.
__global__ void prep_w(const float* __restrict__ W1, const float* __restrict__ W2,
                       unsigned short* __restrict__ wp) {
    int idx = blockIdx.x * blockDim.x + threadIdx.x;
    if (idx >= 24 * 64 * 64) return;
    int lane = idx & 63, nt = (idx >> 6) & 63, k = idx >> 12;
    int scol = (nt << 4) + (lane & 15);
    int lg = lane >> 4;
#pragma unroll
    for (int e = 0; e < 8; ++e) {
        float val;
        if (k < 8) val = W1[(EMBN + k * 32 + lg * 8 + e) * G4 + scol];
        else       val = W2[((k - 8) * 32 + lg * 8 + e) * G4 + scol];
        wp[idx * 8 + e] = f2bf(val);
    }
}

// ---------------- hot-loop macros ----------------
// Load this wave's 8 weight fragments of chunk kk into dst[8] (VGPRs, no LDS).
#define LOADW(dst, kk) do {                                                     \
    _Pragma("unroll")                                                           \
    for (int j_ = 0; j_ < 8; ++j_) {                                            \
        const int nt_ = (j_ >> 1) * 16 + 2 * wid + (j_ & 1);                    \
        dst[j_] = wv[((size_t)(kk) * 64 + nt_) * 64 + lane];                    \
    }                                                                           \
} while (0)

#define MMK(af, W) do {                                                         \
    _Pragma("unroll")                                                           \
    for (int j_ = 0; j_ < 8; ++j_)                                              \
        acc[j_ >> 1][j_ & 1] = __builtin_amdgcn_mfma_f32_16x16x32_bf16(         \
            (af), (W)[j_], acc[j_ >> 1][j_ & 1], 0, 0, 0);                      \
} while (0)

#define ACCZ() do {                                                             \
    _Pragma("unroll") for (int g_ = 0; g_ < 4; ++g_) {                          \
        acc[g_][0] = zf; acc[g_][1] = zf; }                                     \
} while (0)

#define GATHER_EG(dst, tt) do {                                                 \
    _Pragma("unroll")                                                           \
    for (int r_ = 0; r_ < 4; ++r_) {                                            \
        const int tok_ = toks[(lg * 4 + r_) * T_SZ + (tt)];                     \
        _Pragma("unroll")                                                       \
        for (int d_ = 0; d_ < 2; ++d_) {                                        \
            const float* e_ = eg + tok_ * G4 + (2 * wid + d_) * 16 + lc;        \
            dst[0][d_][r_] = e_[0];                                             \
            dst[1][d_][r_] = e_[256];                                           \
            dst[2][d_][r_] = e_[512];                                           \
            dst[3][d_][r_] = e_[768];                                           \
        }                                                                       \
    }                                                                           \
} while (0)

__global__ __launch_bounds__(NTHR, 2)
void lstm_fused(const int* __restrict__ feat, const int* __restrict__ labels,
                const float* __restrict__ eg,
                const bf16x8* __restrict__ wv,
                const float* __restrict__ b2,
                const float* __restrict__ Wd, const float* __restrict__ bd,
                float* __restrict__ out)
{
    __shared__ __align__(16) bf16 h1s[2][TILE * 256];   // 16 KB
    __shared__ __align__(16) bf16 h2s[2][TILE * 256];   // 16 KB
    __shared__ int   toks[TILE * T_SZ];                 // 5 KB
    __shared__ float logitb[TILE][VOCABN + 4];
    __shared__ float lossb[TILE];

    const int tid  = threadIdx.x;
    const int lane = tid & 63;
    const int wid  = tid >> 6;       // wave 0..7: gate-cols (2*wid..2*wid+1)*16 per gate
    const int lc   = lane & 15;
    const int lg   = lane >> 4;
    const int b0   = blockIdx.x * TILE;

    for (int i = tid; i < TILE * 256; i += NTHR) {
        h1s[0][i] = (bf16)0.0f; h1s[1][i] = (bf16)0.0f;
        h2s[0][i] = (bf16)0.0f; h2s[1][i] = (bf16)0.0f;
    }
    for (int i = tid; i < TILE * T_SZ; i += NTHR) {
        int r = i / T_SZ, t = i - r * T_SZ;
        toks[r * T_SZ + t] = feat[(b0 + r) * T_SZ + t];
    }
    __syncthreads();

    float b2v[4][2];
#pragma unroll
    for (int g = 0; g < 4; ++g)
#pragma unroll
        for (int d = 0; d < 2; ++d)
            b2v[g][d] = b2[g * 256 + (2 * wid + d) * 16 + lc];

    const f32x4 zf = {0.f, 0.f, 0.f, 0.f};
    f32x4 acc[4][2];
    float c1s[2][4] = {{0.f,0.f,0.f,0.f},{0.f,0.f,0.f,0.f}};
    float c2s[2][4] = {{0.f,0.f,0.f,0.f},{0.f,0.f,0.f,0.f}};
    float egv[4][2][4], egn[4][2][4];
    bf16x8 wbA[8], wbB[8], a1[8], a2h[8];

    LOADW(wbA, 0);
    GATHER_EG(egv, 0);

    for (int t = 0; t < T_SZ; ++t) {
        const int w = t & 1, r = w ^ 1;
        bf16* h1r = h1s[r]; bf16* h1w = h1s[w];
        bf16* h2r = h2s[r]; bf16* h2w = h2s[w];

        // ============ layer 1: chunks 0..7 (K=256), per-wave pipeline ============
        ACCZ();
#pragma unroll
        for (int k = 0; k < 8; ++k) a1[k] = AFRAG(h1r, k);
        LOADW(wbB, 1);  MMK(a1[0], wbA);
        LOADW(wbA, 2);  MMK(a1[1], wbB);
        LOADW(wbB, 3);  MMK(a1[2], wbA);
        LOADW(wbA, 4);  MMK(a1[3], wbB);
        LOADW(wbB, 5);  MMK(a1[4], wbA);
        LOADW(wbA, 6);  MMK(a1[5], wbB);
        LOADW(wbB, 7);  MMK(a1[6], wbA);
        LOADW(wbA, 8);  MMK(a1[7], wbB);   // prefetch first L2 chunk
        // pointwise L1 -> h1w
#pragma unroll
        for (int d = 0; d < 2; ++d) {
            const int hcol = (2 * wid + d) * 16 + lc;
#pragma unroll
            for (int rr = 0; rr < 4; ++rr) {
                const int row = lg * 4 + rr;
                float gi = acc[0][d][rr] + egv[0][d][rr];
                float gj = acc[1][d][rr] + egv[1][d][rr];
                float gf = acc[2][d][rr] + egv[2][d][rr];
                float go = acc[3][d][rr] + egv[3][d][rr];
                float cn = c1s[d][rr] * sigf(gf + 1.0f) + sigf(gi) * tanhf2(gj);
                float h  = tanhf2(cn) * sigf(go);
                c1s[d][rr] = cn;
                h1w[HSWZ(row, hcol)] = (bf16)h;
            }
        }
        __syncthreads();

        // ============ layer 2: chunks 8..23 (K=512) ============
        ACCZ();
#pragma unroll
        for (int k = 0; k < 8; ++k) a1[k]  = AFRAG(h1w, k);   // x-part: fresh h1_t
#pragma unroll
        for (int k = 0; k < 8; ++k) a2h[k] = AFRAG(h2r, k);   // h-part: h2_{t-1}
        if (t + 1 < T_SZ) GATHER_EG(egn, t + 1);              // hidden under chunks
        LOADW(wbB, 9);   MMK(a1[0], wbA);
        LOADW(wbA, 10);  MMK(a1[1], wbB);
        LOADW(wbB, 11);  MMK(a1[2], wbA);
        LOADW(wbA, 12);  MMK(a1[3], wbB);
        LOADW(wbB, 13);  MMK(a1[4], wbA);
        LOADW(wbA, 14);  MMK(a1[5], wbB);
        LOADW(wbB, 15);  MMK(a1[6], wbA);
        LOADW(wbA, 16);  MMK(a1[7], wbB);
        LOADW(wbB, 17);  MMK(a2h[0], wbA);
        LOADW(wbA, 18);  MMK(a2h[1], wbB);
        LOADW(wbB, 19);  MMK(a2h[2], wbA);
        LOADW(wbA, 20);  MMK(a2h[3], wbB);
        LOADW(wbB, 21);  MMK(a2h[4], wbA);
        LOADW(wbA, 22);  MMK(a2h[5], wbB);
        LOADW(wbB, 23);  MMK(a2h[6], wbA);
        LOADW(wbA, 0);   MMK(a2h[7], wbB);   // prefetch next step's chunk 0
        // pointwise L2 -> h2w
#pragma unroll
        for (int d = 0; d < 2; ++d) {
            const int hcol = (2 * wid + d) * 16 + lc;
#pragma unroll
            for (int rr = 0; rr < 4; ++rr) {
                const int row = lg * 4 + rr;
                float gi = acc[0][d][rr] + b2v[0][d];
                float gj = acc[1][d][rr] + b2v[1][d];
                float gf = acc[2][d][rr] + b2v[2][d];
                float go = acc[3][d][rr] + b2v[3][d];
                float cn = c2s[d][rr] * sigf(gf + 1.0f) + sigf(gi) * tanhf2(gj);
                float h  = tanhf2(cn) * sigf(go);
                c2s[d][rr] = cn;
                h2w[HSWZ(row, hcol)] = (bf16)h;
            }
        }
        // roll eg registers (static copies)
#pragma unroll
        for (int g = 0; g < 4; ++g)
#pragma unroll
            for (int d = 0; d < 2; ++d)
#pragma unroll
                for (int rr = 0; rr < 4; ++rr)
                    egv[g][d][rr] = egn[g][d][rr];
        __syncthreads();
    }

    // ---- epilogue: logits = h2_last @ Wd + bd (T_SZ=80 -> final buffer 1) ----
    const bf16* h2fin = h2s[1];
    for (int pp = tid; pp < TILE * VOCABN; pp += NTHR) {
        int row = pp / VOCABN, v = pp - row * VOCABN;
        float s = bd[v];
        for (int k = 0; k < HID; ++k)
            s += (float)h2fin[HSWZ(row, k)] * Wd[k * VOCABN + v];
        logitb[row][v] = s;
    }
    __syncthreads();
    if (tid < TILE) {
        const int row = tid;
        float m = -1e30f;
        for (int v = 0; v < VOCABN; ++v) m = fmaxf(m, logitb[row][v]);
        float s = 0.f;
        for (int v = 0; v < VOCABN; ++v) s += __expf(logitb[row][v] - m);
        int lab = labels[b0 + row];
        lossb[row] = m + __logf(s) - logitb[row][lab];
    }
    __syncthreads();
    if (tid == 0) {
        float s = 0.f;
#pragma unroll
        for (int rr = 0; rr < TILE; ++rr) s += lossb[rr];
        atomicAdd(out, s * (1.0f / (float)B_SZ));
    }
}

extern "C" void kernel_launch(void* const* d_in, const int* in_sizes, int n_in,
                              void* d_out, int out_size, void* d_ws, size_t ws_size,
                              hipStream_t stream)
{
    (void)in_sizes; (void)n_in; (void)out_size; (void)ws_size;
    const int*   feat   = (const int*)d_in[0];
    const int*   labels = (const int*)d_in[1];
    const float* emb    = (const float*)d_in[2];
    const float* W1     = (const float*)d_in[3];
    const float* b1     = (const float*)d_in[4];
    const float* W2     = (const float*)d_in[5];
    const float* b2     = (const float*)d_in[6];
    const float* Wd     = (const float*)d_in[7];
    const float* bd     = (const float*)d_in[8];
    float* out = (float*)d_out;

    char* ws = (char*)d_ws;
    float* eg = (float*)ws;                         // 327680 B
    bf16*  wp = (bf16*)(ws + 327680);               // 24*64*64*8*2 = 1572864 B

    hipMemsetAsync(d_out, 0, sizeof(float), stream);
    prep_eg<<<(VOCABN * G4 + 255) / 256, 256, 0, stream>>>(emb, W1, b1, eg);
    prep_w<<<(24 * 64 * 64) / 256, 256, 0, stream>>>(W1, W2, (unsigned short*)wp);
    lstm_fused<<<NBLK, NTHR, 0, stream>>>(feat, labels, eg, (const bf16x8*)wp,
                                          b2, Wd, bd, out);
}